// Round 1
// baseline (9955.486 us; speedup 1.0000x reference)
//
#include <hip/hip_runtime.h>
#include <hip/hip_bf16.h>
#include <cstddef>

namespace {

constexpr int B = 16, T = 32, S = 400, E = 128, H = 512, V = 32000, OOV = 50, VEXT = V + OOV;

__device__ __forceinline__ float fsig(float x){ return 1.0f/(1.0f+__expf(-x)); }
__device__ __forceinline__ float ftanh(float x){
  float ax = fabsf(x);
  float t = __expf(-2.0f*ax);
  float r = (1.0f - t)/(1.0f + t);
  return copysignf(r, x);
}

__global__ __launch_bounds__(256) void k_init(const float* __restrict__ h0, const float* __restrict__ c0,
                       float* __restrict__ h, float* __restrict__ c,
                       float* __restrict__ ctx, float* __restrict__ cov){
  int i = blockIdx.x*256 + threadIdx.x;
  if (i < B*H){ h[i]=h0[i]; c[i]=c0[i]; ctx[i]=0.0f; }
  if (i < B*S) cov[i]=0.0f;
}

// enc_proj[b*S+s][k] = sum_h enc[b][s][h] * W_energy[k][H+h] + b_energy[k]
// 400 blocks x 512 threads; each block does 16 rows (register-blocked) x 512 k.
__global__ __launch_bounds__(512) void k_encproj(const float* __restrict__ enc,
                          const float* __restrict__ W_energy,
                          const float* __restrict__ b_energy,
                          float* __restrict__ enc_proj){
  __shared__ float ldsE[16][H];
  const int r0 = blockIdx.x * 16;
  const int tid = threadIdx.x;
  for (int i = tid; i < 16*H; i += 512){
    ldsE[i >> 9][i & 511] = enc[(size_t)(r0 + (i >> 9))*H + (i & 511)];
  }
  __syncthreads();
  const int k = tid;
  const float* wrow = W_energy + (size_t)k*(2*H) + H;
  float acc[16];
  #pragma unroll
  for (int r=0;r<16;++r) acc[r]=0.0f;
  for (int j=0;j<H;j+=4){
    const float4 w = *reinterpret_cast<const float4*>(wrow + j);
    #pragma unroll
    for (int r=0;r<16;++r){
      acc[r] += ldsE[r][j]*w.x + ldsE[r][j+1]*w.y + ldsE[r][j+2]*w.z + ldsE[r][j+3]*w.w;
    }
  }
  const float be = b_energy[k];
  #pragma unroll
  for (int r=0;r<16;++r) enc_proj[(size_t)(r0+r)*H + k] = acc[r] + be;
}

// One block per b: x = [emb_t, ctx] @ W_xctx^T + b_xctx ; gates ; LSTM ; dec_proj = h @ W_d^T
__global__ __launch_bounds__(512) void k_step1(const float* __restrict__ emb, int t,
    const float* __restrict__ W_xctx, const float* __restrict__ b_xctx,
    const float* __restrict__ W_ih, const float* __restrict__ W_hh,
    const float* __restrict__ b_ih, const float* __restrict__ b_hh,
    const float* __restrict__ W_energy,
    float* __restrict__ h, float* __restrict__ c, const float* __restrict__ ctx,
    float* __restrict__ x_out, float* __restrict__ dec_proj){
  const int b = blockIdx.x, tid = threadIdx.x;
  __shared__ float sh_h[H], sh_ctx[H], sh_x[E], sh_emb[E], sh_g[4*H];
  sh_h[tid] = h[b*H + tid];
  sh_ctx[tid] = ctx[b*H + tid];
  if (tid < E) sh_emb[tid] = emb[(size_t)(b*T + t)*E + tid];
  __syncthreads();
  if (tid < E){
    const float* w = W_xctx + (size_t)tid*(E+H);
    float acc = b_xctx[tid];
    for (int j=0;j<E;j+=4){
      float4 wv = *reinterpret_cast<const float4*>(w+j);
      acc += sh_emb[j]*wv.x + sh_emb[j+1]*wv.y + sh_emb[j+2]*wv.z + sh_emb[j+3]*wv.w;
    }
    for (int j=0;j<H;j+=4){
      float4 wv = *reinterpret_cast<const float4*>(w+E+j);
      acc += sh_ctx[j]*wv.x + sh_ctx[j+1]*wv.y + sh_ctx[j+2]*wv.z + sh_ctx[j+3]*wv.w;
    }
    sh_x[tid] = acc;
    x_out[b*E + tid] = acc;
  }
  __syncthreads();
  #pragma unroll
  for (int g=0; g<4; ++g){
    const int row = g*H + tid;
    float acc = b_ih[row] + b_hh[row];
    const float* wi = W_ih + (size_t)row*E;
    for (int j=0;j<E;j+=4){
      float4 wv = *reinterpret_cast<const float4*>(wi+j);
      acc += sh_x[j]*wv.x + sh_x[j+1]*wv.y + sh_x[j+2]*wv.z + sh_x[j+3]*wv.w;
    }
    const float* wh = W_hh + (size_t)row*H;
    for (int j=0;j<H;j+=4){
      float4 wv = *reinterpret_cast<const float4*>(wh+j);
      acc += sh_h[j]*wv.x + sh_h[j+1]*wv.y + sh_h[j+2]*wv.z + sh_h[j+3]*wv.w;
    }
    sh_g[row] = acc;
  }
  __syncthreads();   // gates done; sh_h reads done
  {
    const float ig = fsig(sh_g[tid]);
    const float fg = fsig(sh_g[H+tid]);
    const float gg = ftanh(sh_g[2*H+tid]);
    const float og = fsig(sh_g[3*H+tid]);
    const float cn = fg * c[b*H+tid] + ig*gg;
    const float hn = og * ftanh(cn);
    c[b*H+tid] = cn;
    h[b*H+tid] = hn;
    sh_h[tid] = hn;
  }
  __syncthreads();
  {
    const float* wd = W_energy + (size_t)tid*(2*H);  // W_d = W_energy[:, :H]
    float acc = 0.0f;
    for (int j=0;j<H;j+=4){
      float4 wv = *reinterpret_cast<const float4*>(wd+j);
      acc += sh_h[j]*wv.x + sh_h[j+1]*wv.y + sh_h[j+2]*wv.z + sh_h[j+3]*wv.w;
    }
    dec_proj[b*H + tid] = acc;
  }
}

// grid (100, B), block 256 = 4 waves, one (b,s) per wave.
__global__ __launch_bounds__(256) void k_score(const float* __restrict__ dec_proj,
    const float* __restrict__ enc_proj, const float* __restrict__ W_cov,
    const float* __restrict__ v_attn, const float* __restrict__ cov,
    float* __restrict__ score){
  const int b = blockIdx.y;
  const int wave = threadIdx.x >> 6, lane = threadIdx.x & 63;
  const int s = blockIdx.x*4 + wave;
  const float cv = cov[b*S + s];
  const float* ep = enc_proj + (size_t)(b*S + s)*H;
  const float* dp = dec_proj + b*H;
  float acc = 0.0f;
  const int k0 = lane*8;
  #pragma unroll
  for (int u=0;u<8;++u){
    const int k = k0+u;
    acc += ftanh(dp[k] + ep[k] + cv*W_cov[k]) * v_attn[k];
  }
  #pragma unroll
  for (int off=32; off>0; off>>=1) acc += __shfl_down(acc, off);
  if (lane==0) score[b*S + s] = acc;
}

// One block per b: softmax(score)*mask renorm, ctx, cov+=, hh, p_gen.
__global__ __launch_bounds__(512) void k_soft(const float* __restrict__ score,
    const float* __restrict__ masks, const float* __restrict__ enc,
    const float* __restrict__ h, const float* __restrict__ x,
    const float* __restrict__ W_ad, const float* __restrict__ b_ad,
    const float* __restrict__ W_pgen, const float* __restrict__ b_pgen,
    float* __restrict__ cov, float* __restrict__ probs, float* __restrict__ ctx,
    float* __restrict__ hh, float* __restrict__ p_gen){
  const int b = blockIdx.x, tid = threadIdx.x;
  __shared__ float sp[512];
  __shared__ float red[512];
  __shared__ float sh_h[H], sh_ctx[H];
  sh_h[tid] = h[b*H + tid];
  const float sc = (tid < S) ? score[b*S + tid] : -1e30f;
  red[tid] = sc;
  __syncthreads();
  for (int off=256; off>0; off>>=1){ if (tid<off) red[tid] = fmaxf(red[tid], red[tid+off]); __syncthreads(); }
  const float mx = red[0];
  __syncthreads();
  const float ev = (tid < S) ? __expf(sc - mx) : 0.0f;
  red[tid] = ev;
  __syncthreads();
  for (int off=256; off>0; off>>=1){ if (tid<off) red[tid] += red[tid+off]; __syncthreads(); }
  const float denom = red[0];
  __syncthreads();
  const float p0 = (tid < S) ? (ev/denom) * masks[b*S + tid] : 0.0f;
  red[tid] = p0;
  __syncthreads();
  for (int off=256; off>0; off>>=1){ if (tid<off) red[tid] += red[tid+off]; __syncthreads(); }
  const float psum = red[0];
  __syncthreads();
  const float pr = (tid < S) ? p0/(psum + 1e-12f) : 0.0f;
  sp[tid] = pr;
  if (tid < S){ probs[b*S + tid] = pr; cov[b*S + tid] += pr; }
  __syncthreads();
  // ctx[h] = sum_s probs[s] * enc[b][s][h]   (coalesced across tid)
  {
    const float* eb = enc + (size_t)b*S*H;
    float a0=0.f, a1=0.f;
    for (int si=0; si<S; si+=2){
      a0 += sp[si]   * eb[(size_t)si*H + tid];
      a1 += sp[si+1] * eb[(size_t)(si+1)*H + tid];
    }
    const float cv = a0+a1;
    ctx[b*H + tid] = cv;
    sh_ctx[tid] = cv;
  }
  __syncthreads();
  // hh = [h, ctx] @ W_ad^T + b_ad
  {
    const float* wa = W_ad + (size_t)tid*(2*H);
    float acc = b_ad[tid];
    for (int j=0;j<H;j+=4){
      float4 wv = *reinterpret_cast<const float4*>(wa+j);
      acc += sh_h[j]*wv.x + sh_h[j+1]*wv.y + sh_h[j+2]*wv.z + sh_h[j+3]*wv.w;
    }
    for (int j=0;j<H;j+=4){
      float4 wv = *reinterpret_cast<const float4*>(wa+H+j);
      acc += sh_ctx[j]*wv.x + sh_ctx[j+1]*wv.y + sh_ctx[j+2]*wv.z + sh_ctx[j+3]*wv.w;
    }
    hh[b*H + tid] = acc;
  }
  // p_gen = sigmoid([ctx, h, x] . W_pgen + b_pgen)
  {
    float part = sh_ctx[tid]*W_pgen[tid] + sh_h[tid]*W_pgen[H+tid];
    if (tid < E) part += x[b*E + tid]*W_pgen[2*H + tid];
    red[tid] = part;
    __syncthreads();
    for (int off=256; off>0; off>>=1){ if (tid<off) red[tid] += red[tid+off]; __syncthreads(); }
    if (tid==0) p_gen[b] = fsig(red[0] + b_pgen[0]);
  }
}

// logits[b][v] = hh[b] . W_vocab[v] + b_vocab[v]
// 500 blocks x 256: each wave = 64 v-rows, quarter of K (wave-uniform -> hh via scalar loads).
__global__ __launch_bounds__(256) void k_logits(const float* __restrict__ hh,
    const float* __restrict__ W_vocab, const float* __restrict__ b_vocab,
    float* __restrict__ logits){
  const int tid = threadIdx.x;
  const int lane = tid & 63;
  const int w = __builtin_amdgcn_readfirstlane(tid >> 6);
  const int v = blockIdx.x*64 + lane;
  const float* wp = W_vocab + (size_t)v*H + w*128;
  const float* hp = hh + w*128;
  float acc[16];
  #pragma unroll
  for (int bb=0;bb<16;++bb) acc[bb]=0.0f;
  for (int k=0;k<128;k+=4){
    const float4 wv = *reinterpret_cast<const float4*>(wp + k);
    #pragma unroll
    for (int bb=0;bb<16;++bb){
      const float* hb = hp + bb*H;
      acc[bb] += hb[k]*wv.x + hb[k+1]*wv.y + hb[k+2]*wv.z + hb[k+3]*wv.w;
    }
  }
  __shared__ float red[4][64][17];
  #pragma unroll
  for (int bb=0;bb<16;++bb) red[w][lane][bb] = acc[bb];
  __syncthreads();
  for (int i=tid; i<1024; i+=256){
    const int bb = i >> 6, vl = i & 63;
    const int vv = blockIdx.x*64 + vl;
    logits[(size_t)bb*V + vv] = red[0][vl][bb]+red[1][vl][bb]+red[2][vl][bb]+red[3][vl][bb] + b_vocab[vv];
  }
}

// One block per b: vocab softmax, write out row (V + OOV), scatter-add copy dist.
__global__ __launch_bounds__(1024) void k_final(const float* __restrict__ logits,
    const float* __restrict__ probs, const float* __restrict__ p_gen,
    const int* __restrict__ eidx, const float* __restrict__ extra_zeros,
    float* __restrict__ out, int t){
  const int b = blockIdx.x, tid = threadIdx.x;
  __shared__ float red[1024];
  const float* z = logits + (size_t)b*V;
  float mx = -1e30f;
  for (int v=tid; v<V; v+=1024) mx = fmaxf(mx, z[v]);
  red[tid]=mx; __syncthreads();
  for (int off=512; off>0; off>>=1){ if (tid<off) red[tid]=fmaxf(red[tid],red[tid+off]); __syncthreads(); }
  mx = red[0]; __syncthreads();
  float sum=0.0f;
  for (int v=tid; v<V; v+=1024) sum += __expf(z[v]-mx);
  red[tid]=sum; __syncthreads();
  for (int off=512; off>0; off>>=1){ if (tid<off) red[tid]+=red[tid+off]; __syncthreads(); }
  const float denom = red[0];
  const float pg = p_gen[b];
  const float scl = pg/denom;
  float* orow = out + (size_t)(b*T + t)*VEXT;
  for (int v=tid; v<V; v+=1024) orow[v] = __expf(z[v]-mx)*scl;
  for (int v=V+tid; v<VEXT; v+=1024) orow[v] = extra_zeros[b*OOV + (v-V)];
  __syncthreads();
  const float fac = 1.0f - pg;
  for (int s=tid; s<S; s+=1024) atomicAdd(&orow[eidx[b*S + s]], fac*probs[b*S + s]);
}

} // namespace

extern "C" void kernel_launch(void* const* d_in, const int* in_sizes, int n_in,
                              void* d_out, int out_size, void* d_ws, size_t ws_size,
                              hipStream_t stream){
  const float* emb    = (const float*)d_in[0];
  const float* h0     = (const float*)d_in[1];
  const float* c0     = (const float*)d_in[2];
  const float* enc    = (const float*)d_in[3];
  const float* masks  = (const float*)d_in[4];
  const float* exz    = (const float*)d_in[5];
  const int*   eidx   = (const int*)d_in[6];
  const float* W_ih   = (const float*)d_in[7];
  const float* W_hh   = (const float*)d_in[8];
  const float* b_ih   = (const float*)d_in[9];
  const float* b_hh   = (const float*)d_in[10];
  const float* W_vocab= (const float*)d_in[11];
  const float* b_vocab= (const float*)d_in[12];
  const float* W_cov  = (const float*)d_in[13];
  const float* W_energy=(const float*)d_in[14];
  const float* b_energy=(const float*)d_in[15];
  const float* v_attn = (const float*)d_in[16];
  const float* W_xctx = (const float*)d_in[17];
  const float* b_xctx = (const float*)d_in[18];
  const float* W_ad   = (const float*)d_in[19];
  const float* b_ad   = (const float*)d_in[20];
  const float* W_pgen = (const float*)d_in[21];
  const float* b_pgen = (const float*)d_in[22];

  float* ws = (float*)d_ws;
  float* h     = ws;            // 8192
  float* c     = ws + 8192;     // 8192
  float* ctx   = ws + 16384;    // 8192
  float* x     = ws + 24576;    // 2048
  float* dec   = ws + 26624;    // 8192
  float* hh    = ws + 34816;    // 8192
  float* pg    = ws + 43008;    // 16
  float* score = ws + 43024;    // 6400
  float* probs = ws + 49424;    // 6400
  float* cov   = ws + 55824;    // 6400
  float* logits= ws + 62224;    // 512000
  float* encp  = ws + 574224;   // 3276800
  float* outp  = (float*)d_out;

  k_init<<<32,256,0,stream>>>(h0,c0,h,c,ctx,cov);
  k_encproj<<<400,512,0,stream>>>(enc,W_energy,b_energy,encp);
  for (int t=0;t<T;++t){
    k_step1<<<16,512,0,stream>>>(emb,t,W_xctx,b_xctx,W_ih,W_hh,b_ih,b_hh,W_energy,h,c,ctx,x,dec);
    k_score<<<dim3(100,16),256,0,stream>>>(dec,encp,W_cov,v_attn,cov,score);
    k_soft<<<16,512,0,stream>>>(score,masks,enc,h,x,W_ad,b_ad,W_pgen,b_pgen,cov,probs,ctx,hh,pg);
    k_logits<<<500,256,0,stream>>>(hh,W_vocab,b_vocab,logits);
    k_final<<<16,1024,0,stream>>>(logits,probs,pg,eidx,exz,outp,t);
  }
}

// Round 2
// 4304.943 us; speedup vs baseline: 2.3126x; 2.3126x over previous
//
#include <hip/hip_runtime.h>
#include <hip/hip_bf16.h>
#include <cstddef>

namespace {

constexpr int B = 16, T = 32, S = 400, E = 128, H = 512, V = 32000, OOV = 50, VEXT = V + OOV;

__device__ __forceinline__ float fsig(float x){ return 1.0f/(1.0f+__expf(-x)); }
__device__ __forceinline__ float ftanh(float x){
  float ax = fabsf(x);
  float t = __expf(-2.0f*ax);
  float r = (1.0f - t)/(1.0f + t);
  return copysignf(r, x);
}

__global__ __launch_bounds__(256) void k_init(const float* __restrict__ h0, const float* __restrict__ c0,
                       float* __restrict__ h, float* __restrict__ c,
                       float* __restrict__ cov){
  int i = blockIdx.x*256 + threadIdx.x;
  if (i < B*H){ h[i]=h0[i]; c[i]=c0[i]; }
  if (i < B*S) cov[i]=0.0f;
}

// x0[b][j] = emb[b][0][:] . W_xctx[j][:E] + b_xctx[j]   (ctx_0 = 0)
__global__ __launch_bounds__(128) void k_x0(const float* __restrict__ emb,
    const float* __restrict__ W_xctx, const float* __restrict__ b_xctx,
    float* __restrict__ x0){
  const int b = blockIdx.x, tid = threadIdx.x;
  __shared__ float se[E];
  se[tid] = emb[(size_t)(b*T)*E + tid];
  __syncthreads();
  const float* w = W_xctx + (size_t)tid*(E+H);
  float acc = b_xctx[tid];
  #pragma unroll 8
  for (int k=0;k<E;k+=4){
    float4 wv = *reinterpret_cast<const float4*>(w+k);
    acc += se[k]*wv.x + se[k+1]*wv.y + se[k+2]*wv.z + se[k+3]*wv.w;
  }
  x0[b*E + tid] = acc;
}

// enc_proj: 400 blocks x 512 threads; 16 rows register-blocked x 512 k.
__global__ __launch_bounds__(512) void k_encproj(const float* __restrict__ enc,
                          const float* __restrict__ W_energy,
                          const float* __restrict__ b_energy,
                          float* __restrict__ enc_proj){
  __shared__ float ldsE[16][H];
  const int r0 = blockIdx.x * 16;
  const int tid = threadIdx.x;
  for (int i = tid; i < 16*H; i += 512){
    ldsE[i >> 9][i & 511] = enc[(size_t)(r0 + (i >> 9))*H + (i & 511)];
  }
  __syncthreads();
  const int k = tid;
  const float* wrow = W_energy + (size_t)k*(2*H) + H;
  float acc[16];
  #pragma unroll
  for (int r=0;r<16;++r) acc[r]=0.0f;
  for (int j=0;j<H;j+=4){
    const float4 w = *reinterpret_cast<const float4*>(wrow + j);
    #pragma unroll
    for (int r=0;r<16;++r){
      acc[r] += ldsE[r][j]*w.x + ldsE[r][j+1]*w.y + ldsE[r][j+2]*w.z + ldsE[r][j+3]*w.w;
    }
  }
  const float be = b_energy[k];
  #pragma unroll
  for (int r=0;r<16;++r) enc_proj[(size_t)(r0+r)*H + k] = acc[r] + be;
}

// grid (16 b, 8 jc) x 256: gates GEMM (4 gates x 64 j per block) + fused LSTM elementwise.
// Reads hold/cold (parity p), writes hnew/cnew (parity p^1) -> no cross-block h race.
__global__ __launch_bounds__(256) void k_gates(
    const float* __restrict__ x, const float* __restrict__ hold,
    const float* __restrict__ cold,
    const float* __restrict__ W_ih, const float* __restrict__ W_hh,
    const float* __restrict__ b_ih, const float* __restrict__ b_hh,
    float* __restrict__ hnew, float* __restrict__ cnew){
  const int b = blockIdx.x, jc = blockIdx.y, tid = threadIdx.x;
  __shared__ float xh[E+H];
  __shared__ float sg[4][64];
  for (int i=tid; i<E+H; i+=256)
    xh[i] = (i<E) ? x[b*E+i] : hold[b*H + (i-E)];
  __syncthreads();
  const int l = tid & 63, g = tid >> 6;
  const int j = jc*64 + l;
  const int row = g*H + j;
  float acc = b_ih[row] + b_hh[row];
  const float* wi = W_ih + (size_t)row*E;
  #pragma unroll 8
  for (int k=0;k<E;k+=4){
    float4 w = *reinterpret_cast<const float4*>(wi+k);
    acc += xh[k]*w.x + xh[k+1]*w.y + xh[k+2]*w.z + xh[k+3]*w.w;
  }
  const float* wh = W_hh + (size_t)row*H;
  #pragma unroll 8
  for (int k=0;k<H;k+=4){
    float4 w = *reinterpret_cast<const float4*>(wh+k);
    acc += xh[E+k]*w.x + xh[E+k+1]*w.y + xh[E+k+2]*w.z + xh[E+k+3]*w.w;
  }
  sg[g][l] = acc;
  __syncthreads();
  if (tid < 64){
    const float ig = fsig(sg[0][tid]);
    const float fg = fsig(sg[1][tid]);
    const float gg = ftanh(sg[2][tid]);
    const float og = fsig(sg[3][tid]);
    const int idx = b*H + jc*64 + tid;
    const float cn = fg*cold[idx] + ig*gg;
    cnew[idx] = cn;
    hnew[idx] = og*ftanh(cn);
  }
}

// dec_proj = h @ W_d^T ; grid (16 b, 4 jc) x 128.
__global__ __launch_bounds__(128) void k_dec(const float* __restrict__ h,
    const float* __restrict__ W_energy, float* __restrict__ dec){
  const int b = blockIdx.x, jc = blockIdx.y, tid = threadIdx.x;
  __shared__ float sh[H];
  for (int i=tid;i<H;i+=128) sh[i]=h[b*H+i];
  __syncthreads();
  const int j = jc*128 + tid;
  const float* w = W_energy + (size_t)j*(2*H);
  float acc=0.0f;
  #pragma unroll 8
  for (int k=0;k<H;k+=4){
    float4 wv = *reinterpret_cast<const float4*>(w+k);
    acc += sh[k]*wv.x + sh[k+1]*wv.y + sh[k+2]*wv.z + sh[k+3]*wv.w;
  }
  dec[b*H+j]=acc;
}

// grid (100, B), block 256 = 4 waves, one (b,s) per wave.
__global__ __launch_bounds__(256) void k_score(const float* __restrict__ dec_proj,
    const float* __restrict__ enc_proj, const float* __restrict__ W_cov,
    const float* __restrict__ v_attn, const float* __restrict__ cov,
    float* __restrict__ score){
  const int b = blockIdx.y;
  const int wave = threadIdx.x >> 6, lane = threadIdx.x & 63;
  const int s = blockIdx.x*4 + wave;
  const float cv = cov[b*S + s];
  const float* ep = enc_proj + (size_t)(b*S + s)*H;
  const float* dp = dec_proj + b*H;
  float acc = 0.0f;
  const int k0 = lane*8;
  #pragma unroll
  for (int u=0;u<8;++u){
    const int k = k0+u;
    acc += ftanh(dp[k] + ep[k] + cv*W_cov[k]) * v_attn[k];
  }
  #pragma unroll
  for (int off=32; off>0; off>>=1) acc += __shfl_down(acc, off);
  if (lane==0) score[b*S + s] = acc;
}

// grid (16 b, 8 hc) x 256: redundant per-b softmax (cheap), then 64-col ctx slice.
// hc==0 block also writes probs + cov update.
__global__ __launch_bounds__(256) void k_ctx(const float* __restrict__ score,
    const float* __restrict__ masks, const float* __restrict__ enc,
    float* __restrict__ cov, float* __restrict__ probs, float* __restrict__ ctx){
  const int b = blockIdx.x, hc = blockIdx.y, tid = threadIdx.x;
  __shared__ float red[256];
  __shared__ float sp[512];
  const float sc0 = (tid < S)      ? score[b*S + tid]       : -1e30f;
  const float sc1 = (tid+256 < S)  ? score[b*S + tid + 256] : -1e30f;
  red[tid] = fmaxf(sc0, sc1);
  __syncthreads();
  for (int off=128; off>0; off>>=1){ if (tid<off) red[tid]=fmaxf(red[tid],red[tid+off]); __syncthreads(); }
  const float mx = red[0];
  __syncthreads();
  const float e0 = (tid < S)     ? __expf(sc0 - mx) : 0.0f;
  const float e1 = (tid+256 < S) ? __expf(sc1 - mx) : 0.0f;
  red[tid] = e0 + e1;
  __syncthreads();
  for (int off=128; off>0; off>>=1){ if (tid<off) red[tid]+=red[tid+off]; __syncthreads(); }
  const float den = red[0];
  __syncthreads();
  const float p0 = (tid < S)     ? (e0/den)*masks[b*S+tid]     : 0.0f;
  const float p1 = (tid+256 < S) ? (e1/den)*masks[b*S+tid+256] : 0.0f;
  red[tid] = p0 + p1;
  __syncthreads();
  for (int off=128; off>0; off>>=1){ if (tid<off) red[tid]+=red[tid+off]; __syncthreads(); }
  const float inv = 1.0f/(red[0] + 1e-12f);
  __syncthreads();
  const float pr0 = p0*inv, pr1 = p1*inv;
  sp[tid] = pr0; sp[tid+256] = pr1;
  if (hc==0){
    if (tid < S){ probs[b*S+tid] = pr0; cov[b*S+tid] += pr0; }
    if (tid+256 < S){ probs[b*S+tid+256] = pr1; cov[b*S+tid+256] += pr1; }
  }
  __syncthreads();
  // ctx slice: cols [hc*64, hc*64+64), 4 s-groups
  const int c = tid & 63, sg_ = tid >> 6;
  const float* eb = enc + (size_t)b*S*H + hc*64 + c;
  float acc = 0.0f;
  for (int s=sg_; s<S; s+=4) acc += sp[s]*eb[(size_t)s*H];
  red[tid] = acc;
  __syncthreads();
  if (tid < 64)
    ctx[b*H + hc*64 + tid] = red[tid]+red[tid+64]+red[tid+128]+red[tid+192];
}

// grid (16 b, 5 jc) x 128: jc<4 -> 128 hh rows each; jc==4 -> p_gen + x_{t+1}.
__global__ __launch_bounds__(128) void k_post(const float* __restrict__ h,
    const float* __restrict__ ctxg, const float* __restrict__ xcur,
    const float* __restrict__ emb, int tnext,
    const float* __restrict__ W_ad, const float* __restrict__ b_ad,
    const float* __restrict__ W_pgen, const float* __restrict__ b_pgen,
    const float* __restrict__ W_xctx, const float* __restrict__ b_xctx,
    float* __restrict__ hh, float* __restrict__ pgen, float* __restrict__ xnext){
  const int b = blockIdx.x, jc = blockIdx.y, tid = threadIdx.x;
  __shared__ float sh_[H], sc_[H], sx_[E], se_[E];
  __shared__ float red[128];
  for (int i=tid;i<H;i+=128){ sh_[i]=h[b*H+i]; sc_[i]=ctxg[b*H+i]; }
  if (jc==4){
    sx_[tid] = xcur[b*E + tid];
    se_[tid] = emb[(size_t)(b*T + tnext)*E + tid];
  }
  __syncthreads();
  if (jc < 4){
    const int j = jc*128 + tid;
    const float* w = W_ad + (size_t)j*(2*H);
    float acc = b_ad[j];
    #pragma unroll 8
    for (int k=0;k<H;k+=4){
      float4 wv = *reinterpret_cast<const float4*>(w+k);
      acc += sh_[k]*wv.x + sh_[k+1]*wv.y + sh_[k+2]*wv.z + sh_[k+3]*wv.w;
    }
    #pragma unroll 8
    for (int k=0;k<H;k+=4){
      float4 wv = *reinterpret_cast<const float4*>(w+H+k);
      acc += sc_[k]*wv.x + sc_[k+1]*wv.y + sc_[k+2]*wv.z + sc_[k+3]*wv.w;
    }
    hh[b*H + j] = acc;
  } else {
    // p_gen = sigmoid([ctx, h, x] . W_pgen + b_pgen)
    float part = 0.0f;
    for (int k=tid; k<2*H+E; k+=128){
      const float v = (k<H) ? sc_[k] : ((k<2*H) ? sh_[k-H] : sx_[k-2*H]);
      part += v * W_pgen[k];
    }
    red[tid] = part;
    __syncthreads();
    for (int off=64; off>0; off>>=1){ if (tid<off) red[tid]+=red[tid+off]; __syncthreads(); }
    if (tid==0) pgen[b] = fsig(red[0] + b_pgen[0]);
    // x_{t+1} = [emb_{t+1}, ctx_t] @ W_xctx^T + b_xctx
    const float* w = W_xctx + (size_t)tid*(E+H);
    float acc = b_xctx[tid];
    #pragma unroll 8
    for (int k=0;k<E;k+=4){
      float4 wv = *reinterpret_cast<const float4*>(w+k);
      acc += se_[k]*wv.x + se_[k+1]*wv.y + se_[k+2]*wv.z + se_[k+3]*wv.w;
    }
    #pragma unroll 8
    for (int k=0;k<H;k+=4){
      float4 wv = *reinterpret_cast<const float4*>(w+E+k);
      acc += sc_[k]*wv.x + sc_[k+1]*wv.y + sc_[k+2]*wv.z + sc_[k+3]*wv.w;
    }
    xnext[b*E + tid] = acc;
  }
}

// logits[b][v] = hh[b] . W_vocab[v] + b_vocab[v]
__global__ __launch_bounds__(256) void k_logits(const float* __restrict__ hh,
    const float* __restrict__ W_vocab, const float* __restrict__ b_vocab,
    float* __restrict__ logits){
  const int tid = threadIdx.x;
  const int lane = tid & 63;
  const int w = __builtin_amdgcn_readfirstlane(tid >> 6);
  const int v = blockIdx.x*64 + lane;
  const float* wp = W_vocab + (size_t)v*H + w*128;
  const float* hp = hh + w*128;
  float acc[16];
  #pragma unroll
  for (int bb=0;bb<16;++bb) acc[bb]=0.0f;
  for (int k=0;k<128;k+=4){
    const float4 wv = *reinterpret_cast<const float4*>(wp + k);
    #pragma unroll
    for (int bb=0;bb<16;++bb){
      const float* hb = hp + bb*H;
      acc[bb] += hb[k]*wv.x + hb[k+1]*wv.y + hb[k+2]*wv.z + hb[k+3]*wv.w;
    }
  }
  __shared__ float red[4][64][17];
  #pragma unroll
  for (int bb=0;bb<16;++bb) red[w][lane][bb] = acc[bb];
  __syncthreads();
  for (int i=tid; i<1024; i+=256){
    const int bb = i >> 6, vl = i & 63;
    const int vv = blockIdx.x*64 + vl;
    logits[(size_t)bb*V + vv] = red[0][vl][bb]+red[1][vl][bb]+red[2][vl][bb]+red[3][vl][bb] + b_vocab[vv];
  }
}

// One block per b: vocab softmax, write out row (V + OOV), scatter-add copy dist.
__global__ __launch_bounds__(1024) void k_final(const float* __restrict__ logits,
    const float* __restrict__ probs, const float* __restrict__ p_gen,
    const int* __restrict__ eidx, const float* __restrict__ extra_zeros,
    float* __restrict__ out, int t){
  const int b = blockIdx.x, tid = threadIdx.x;
  __shared__ float red[1024];
  const float* z = logits + (size_t)b*V;
  float mx = -1e30f;
  for (int v=tid; v<V; v+=1024) mx = fmaxf(mx, z[v]);
  red[tid]=mx; __syncthreads();
  for (int off=512; off>0; off>>=1){ if (tid<off) red[tid]=fmaxf(red[tid],red[tid+off]); __syncthreads(); }
  mx = red[0]; __syncthreads();
  float sum=0.0f;
  for (int v=tid; v<V; v+=1024) sum += __expf(z[v]-mx);
  red[tid]=sum; __syncthreads();
  for (int off=512; off>0; off>>=1){ if (tid<off) red[tid]+=red[tid+off]; __syncthreads(); }
  const float denom = red[0];
  const float pg = p_gen[b];
  const float scl = pg/denom;
  float* orow = out + (size_t)(b*T + t)*VEXT;
  for (int v=tid; v<V; v+=1024) orow[v] = __expf(z[v]-mx)*scl;
  for (int v=V+tid; v<VEXT; v+=1024) orow[v] = extra_zeros[b*OOV + (v-V)];
  __syncthreads();
  const float fac = 1.0f - pg;
  for (int s=tid; s<S; s+=1024) atomicAdd(&orow[eidx[b*S + s]], fac*probs[b*S + s]);
}

} // namespace

extern "C" void kernel_launch(void* const* d_in, const int* in_sizes, int n_in,
                              void* d_out, int out_size, void* d_ws, size_t ws_size,
                              hipStream_t stream){
  const float* emb    = (const float*)d_in[0];
  const float* h0     = (const float*)d_in[1];
  const float* c0     = (const float*)d_in[2];
  const float* enc    = (const float*)d_in[3];
  const float* masks  = (const float*)d_in[4];
  const float* exz    = (const float*)d_in[5];
  const int*   eidx   = (const int*)d_in[6];
  const float* W_ih   = (const float*)d_in[7];
  const float* W_hh   = (const float*)d_in[8];
  const float* b_ih   = (const float*)d_in[9];
  const float* b_hh   = (const float*)d_in[10];
  const float* W_vocab= (const float*)d_in[11];
  const float* b_vocab= (const float*)d_in[12];
  const float* W_cov  = (const float*)d_in[13];
  const float* W_energy=(const float*)d_in[14];
  const float* b_energy=(const float*)d_in[15];
  const float* v_attn = (const float*)d_in[16];
  const float* W_xctx = (const float*)d_in[17];
  const float* b_xctx = (const float*)d_in[18];
  const float* W_ad   = (const float*)d_in[19];
  const float* b_ad   = (const float*)d_in[20];
  const float* W_pgen = (const float*)d_in[21];
  const float* b_pgen = (const float*)d_in[22];

  float* ws = (float*)d_ws;
  float* hbuf  = ws;             // 2 x 8192
  float* cbuf  = ws + 16384;     // 2 x 8192
  float* ctx   = ws + 32768;     // 8192
  float* xbuf  = ws + 40960;     // 2 x 2048
  float* dec   = ws + 45056;     // 8192
  float* hh    = ws + 53248;     // 8192
  float* pg    = ws + 61440;     // 16
  float* score = ws + 61456;     // 6400
  float* probs = ws + 67856;     // 6400
  float* cov   = ws + 74256;     // 6400
  float* logits= ws + 80656;     // 512000
  float* encp  = ws + 592656;    // 3276800
  float* outp  = (float*)d_out;

  k_init<<<32,256,0,stream>>>(h0,c0,hbuf,cbuf,cov);
  k_x0<<<16,128,0,stream>>>(emb,W_xctx,b_xctx,xbuf);
  k_encproj<<<400,512,0,stream>>>(enc,W_energy,b_energy,encp);
  for (int t=0;t<T;++t){
    const int p = t&1;
    const float* hold = hbuf + p*8192;
    const float* cold = cbuf + p*8192;
    float* hnew = hbuf + (p^1)*8192;
    float* cnew = cbuf + (p^1)*8192;
    const float* xcur = xbuf + p*2048;
    float* xnext = xbuf + (p^1)*2048;
    const int tnext = (t+1 < T) ? (t+1) : (T-1);
    k_gates<<<dim3(16,8),256,0,stream>>>(xcur,hold,cold,W_ih,W_hh,b_ih,b_hh,hnew,cnew);
    k_dec<<<dim3(16,4),128,0,stream>>>(hnew,W_energy,dec);
    k_score<<<dim3(100,16),256,0,stream>>>(dec,encp,W_cov,v_attn,cov,score);
    k_ctx<<<dim3(16,8),256,0,stream>>>(score,masks,enc,cov,probs,ctx);
    k_post<<<dim3(16,5),128,0,stream>>>(hnew,ctx,xcur,emb,tnext,W_ad,b_ad,W_pgen,b_pgen,W_xctx,b_xctx,hh,pg,xnext);
    k_logits<<<500,256,0,stream>>>(hh,W_vocab,b_vocab,logits);
    k_final<<<16,1024,0,stream>>>(logits,probs,pg,eidx,exz,outp,t);
  }
}

// Round 3
// 4299.902 us; speedup vs baseline: 2.3153x; 1.0012x over previous
//
#include <hip/hip_runtime.h>
#include <hip/hip_bf16.h>
#include <cstddef>

namespace {

constexpr int B = 16, T = 32, S = 400, E = 128, H = 512, V = 32000, OOV = 50, VEXT = V + OOV;

__device__ __forceinline__ float fsig(float x){ return 1.0f/(1.0f+__expf(-x)); }
__device__ __forceinline__ float ftanh(float x){
  float ax = fabsf(x);
  float t = __expf(-2.0f*ax);
  float r = (1.0f - t)/(1.0f + t);
  return copysignf(r, x);
}

__global__ __launch_bounds__(256) void k_init(const float* __restrict__ h0, const float* __restrict__ c0,
                       float* __restrict__ h, float* __restrict__ c,
                       float* __restrict__ cov){
  int i = blockIdx.x*256 + threadIdx.x;
  if (i < B*H){ h[i]=h0[i]; c[i]=c0[i]; }
  if (i < B*S) cov[i]=0.0f;
}

// x0[b][j] = emb[b][0][:] . W_xctx[j][:E] + b_xctx[j]   (ctx_0 = 0)
__global__ __launch_bounds__(128) void k_x0(const float* __restrict__ emb,
    const float* __restrict__ W_xctx, const float* __restrict__ b_xctx,
    float* __restrict__ x0){
  const int b = blockIdx.x, tid = threadIdx.x;
  __shared__ float se[E];
  se[tid] = emb[(size_t)(b*T)*E + tid];
  __syncthreads();
  const float* w = W_xctx + (size_t)tid*(E+H);
  float acc = b_xctx[tid];
  #pragma unroll 8
  for (int k=0;k<E;k+=4){
    float4 wv = *reinterpret_cast<const float4*>(w+k);
    acc += se[k]*wv.x + se[k+1]*wv.y + se[k+2]*wv.z + se[k+3]*wv.w;
  }
  x0[b*E + tid] = acc;
}

// Wt[j][k] = W_energy[k][H+j]  (512x512), tiled transpose. grid (16,16) x 256.
__global__ __launch_bounds__(256) void k_trw(const float* __restrict__ W_energy,
                                             float* __restrict__ Wt){
  __shared__ float tile[32][33];
  const int j0 = blockIdx.x*32, k0 = blockIdx.y*32;
  const int tx = threadIdx.x & 31, ty = threadIdx.x >> 5;  // 8 rows
  #pragma unroll
  for (int r=0;r<4;++r)
    tile[ty+8*r][tx] = W_energy[(size_t)(k0+ty+8*r)*(2*H) + H + j0 + tx];
  __syncthreads();
  #pragma unroll
  for (int r=0;r<4;++r)
    Wt[(size_t)(j0+ty+8*r)*H + k0 + tx] = tile[tx][ty+8*r];
}

// enc_proj: 400 blocks x 512 threads; 16 s-rows register-blocked x 512 k.
// Wt gives coalesced weight loads; LDS enc reads explicit float4 broadcast.
__global__ __launch_bounds__(512) void k_encproj(const float* __restrict__ enc,
                          const float* __restrict__ Wt,
                          const float* __restrict__ b_energy,
                          float* __restrict__ enc_proj){
  __shared__ float ldsE[16][H];
  const int r0 = blockIdx.x * 16;
  const int tid = threadIdx.x;
  for (int i = tid; i < 16*(H/4); i += 512){
    const int r = i >> 7, c = i & 127;
    *reinterpret_cast<float4*>(&ldsE[r][c*4]) =
        *reinterpret_cast<const float4*>(&enc[(size_t)(r0+r)*H + c*4]);
  }
  __syncthreads();
  const int k = tid;
  float acc[16];
  #pragma unroll
  for (int r=0;r<16;++r) acc[r]=0.0f;
  for (int j=0;j<H;j+=4){
    const float w0 = Wt[(size_t) j   *H + k];
    const float w1 = Wt[(size_t)(j+1)*H + k];
    const float w2 = Wt[(size_t)(j+2)*H + k];
    const float w3 = Wt[(size_t)(j+3)*H + k];
    #pragma unroll
    for (int r=0;r<16;++r){
      const float4 e = *reinterpret_cast<const float4*>(&ldsE[r][j]);
      acc[r] += e.x*w0 + e.y*w1 + e.z*w2 + e.w*w3;
    }
  }
  const float be = b_energy[k];
  #pragma unroll
  for (int r=0;r<16;++r) enc_proj[(size_t)(r0+r)*H + k] = acc[r] + be;
}

// scatter copy-dist for step tprev into already-written out rows.
__device__ __forceinline__ void do_scatter(const float* __restrict__ probs,
    const float* __restrict__ pg, const int* __restrict__ eidx,
    float* __restrict__ out, int tprev, int idx0, int stride){
  for (int i = idx0; i < B*S; i += stride){
    const int b = i / S, s = i - b*S;
    float* orow = out + (size_t)(b*T + tprev)*VEXT;
    atomicAdd(&orow[eidx[b*S + s]], (1.0f - pg[b])*probs[b*S + s]);
  }
}

// grid 68 x 256. blocks 0..63: gates GEMM multi-b (16 j x 4 gates x 8 b) + LSTM.
// blocks 64..67: scatter-add for step t-1 (runs concurrently; safe: probs/pg
// still hold step t-1 values until k_ctx/k_post of this step).
__global__ __launch_bounds__(256) void k_gates(
    const float* __restrict__ x, const float* __restrict__ hold,
    const float* __restrict__ cold,
    const float* __restrict__ W_ih, const float* __restrict__ W_hh,
    const float* __restrict__ b_ih, const float* __restrict__ b_hh,
    float* __restrict__ hnew, float* __restrict__ cnew,
    const float* __restrict__ probs_prev, const float* __restrict__ pg_prev,
    const int* __restrict__ eidx, float* __restrict__ out, int t){
  const int blk = blockIdx.x, tid = threadIdx.x;
  if (blk >= 64){
    if (t > 0) do_scatter(probs_prev, pg_prev, eidx, out, t-1, (blk-64)*256 + tid, 4*256);
    return;
  }
  const int gb = blk >> 1, bh = blk & 1, b0 = bh*8;
  __shared__ float xh[8][640];
  __shared__ float sg[4][64][9];
  for (int b=0;b<8;++b)
    for (int k=tid;k<640;k+=256)
      xh[b][k] = (k<E) ? x[(b0+b)*E + k] : hold[(b0+b)*H + (k-E)];
  __syncthreads();
  const int w = tid >> 6, l = tid & 63, g = l >> 4, jj = l & 15;
  const int row = g*H + gb*16 + jj;
  float acc[8];
  #pragma unroll
  for (int b=0;b<8;++b) acc[b]=0.0f;
  const int ks = w*160, ke = ks + 160;
  if (ks < 128){   // only wave 0: W_ih segment k in [0,128)
    const float* wr = W_ih + (size_t)row*E;
    for (int k=0;k<128;k+=4){
      const float4 wv = *reinterpret_cast<const float4*>(wr + k);
      #pragma unroll
      for (int b=0;b<8;++b){
        const float4 xv = *reinterpret_cast<const float4*>(&xh[b][k]);
        acc[b] += xv.x*wv.x + xv.y*wv.y + xv.z*wv.z + xv.w*wv.w;
      }
    }
  }
  {
    const int hs = (ks < 128) ? 128 : ks;
    const float* wr = W_hh + (size_t)row*H - 128;   // wr[k] == W_hh[row][k-128]
    for (int k=hs;k<ke;k+=4){
      const float4 wv = *reinterpret_cast<const float4*>(wr + k);
      #pragma unroll
      for (int b=0;b<8;++b){
        const float4 xv = *reinterpret_cast<const float4*>(&xh[b][k]);
        acc[b] += xv.x*wv.x + xv.y*wv.y + xv.z*wv.z + xv.w*wv.w;
      }
    }
  }
  #pragma unroll
  for (int b=0;b<8;++b) sg[w][l][b] = acc[b];
  __syncthreads();
  if (tid < 128){
    const int b = tid >> 4, j2 = tid & 15;
    float gs[4];
    #pragma unroll
    for (int g2=0;g2<4;++g2){
      const int ll = g2*16 + j2;
      const int rw = g2*H + gb*16 + j2;
      gs[g2] = sg[0][ll][b]+sg[1][ll][b]+sg[2][ll][b]+sg[3][ll][b] + b_ih[rw] + b_hh[rw];
    }
    const float ig = fsig(gs[0]);
    const float fg = fsig(gs[1]);
    const float gg = ftanh(gs[2]);
    const float og = fsig(gs[3]);
    const int idx = (b0+b)*H + gb*16 + j2;
    const float cn = fg*cold[idx] + ig*gg;
    cnew[idx] = cn;
    hnew[idx] = og*ftanh(cn);
  }
}

// dec_proj = h @ W_d^T ; grid 16 x 256: 8 j-blocks x 2 b-halves, multi-b.
__global__ __launch_bounds__(256) void k_dec(const float* __restrict__ h,
    const float* __restrict__ W_energy, float* __restrict__ dec){
  const int blk = blockIdx.x, tid = threadIdx.x;
  const int gb = blk >> 1, bh = blk & 1, b0 = bh*8;
  __shared__ float sh[8][512];
  __shared__ float sg[4][64][9];
  for (int b=0;b<8;++b)
    for (int k=tid;k<H;k+=256) sh[b][k] = h[(b0+b)*H + k];
  __syncthreads();
  const int w = tid >> 6, l = tid & 63;
  const int j = gb*64 + l;
  const float* wr = W_energy + (size_t)j*(2*H);
  float acc[8];
  #pragma unroll
  for (int b=0;b<8;++b) acc[b]=0.0f;
  for (int k=w*128;k<w*128+128;k+=4){
    const float4 wv = *reinterpret_cast<const float4*>(wr + k);
    #pragma unroll
    for (int b=0;b<8;++b){
      const float4 xv = *reinterpret_cast<const float4*>(&sh[b][k]);
      acc[b] += xv.x*wv.x + xv.y*wv.y + xv.z*wv.z + xv.w*wv.w;
    }
  }
  #pragma unroll
  for (int b=0;b<8;++b) sg[w][l][b] = acc[b];
  __syncthreads();
  for (int i=tid;i<512;i+=256){
    const int jl = i & 63, b = i >> 6;
    dec[(b0+b)*H + gb*64 + jl] = sg[0][jl][b]+sg[1][jl][b]+sg[2][jl][b]+sg[3][jl][b];
  }
}

// grid (100, B), block 256 = 4 waves, one (b,s) per wave.
__global__ __launch_bounds__(256) void k_score(const float* __restrict__ dec_proj,
    const float* __restrict__ enc_proj, const float* __restrict__ W_cov,
    const float* __restrict__ v_attn, const float* __restrict__ cov,
    float* __restrict__ score){
  const int b = blockIdx.y;
  const int wave = threadIdx.x >> 6, lane = threadIdx.x & 63;
  const int s = blockIdx.x*4 + wave;
  const float cv = cov[b*S + s];
  const float* ep = enc_proj + (size_t)(b*S + s)*H;
  const float* dp = dec_proj + b*H;
  float acc = 0.0f;
  const int k0 = lane*8;
  #pragma unroll
  for (int u=0;u<8;++u){
    const int k = k0+u;
    acc += ftanh(dp[k] + ep[k] + cv*W_cov[k]) * v_attn[k];
  }
  #pragma unroll
  for (int off=32; off>0; off>>=1) acc += __shfl_down(acc, off);
  if (lane==0) score[b*S + s] = acc;
}

// grid (16 b, 8 hc) x 256: redundant per-b softmax, then 64-col ctx slice.
// hc==0 also writes probs + cov update and zeroes vsum[b] for this step.
__global__ __launch_bounds__(256) void k_ctx(const float* __restrict__ score,
    const float* __restrict__ masks, const float* __restrict__ enc,
    float* __restrict__ cov, float* __restrict__ probs, float* __restrict__ ctx,
    float* __restrict__ vsum){
  const int b = blockIdx.x, hc = blockIdx.y, tid = threadIdx.x;
  __shared__ float red[256];
  __shared__ float sp[512];
  if (hc==0 && tid==0) vsum[b] = 0.0f;
  const float sc0 = (tid < S)      ? score[b*S + tid]       : -1e30f;
  const float sc1 = (tid+256 < S)  ? score[b*S + tid + 256] : -1e30f;
  red[tid] = fmaxf(sc0, sc1);
  __syncthreads();
  for (int off=128; off>0; off>>=1){ if (tid<off) red[tid]=fmaxf(red[tid],red[tid+off]); __syncthreads(); }
  const float mx = red[0];
  __syncthreads();
  const float e0 = (tid < S)     ? __expf(sc0 - mx) : 0.0f;
  const float e1 = (tid+256 < S) ? __expf(sc1 - mx) : 0.0f;
  red[tid] = e0 + e1;
  __syncthreads();
  for (int off=128; off>0; off>>=1){ if (tid<off) red[tid]+=red[tid+off]; __syncthreads(); }
  const float den = red[0];
  __syncthreads();
  const float p0 = (tid < S)     ? (e0/den)*masks[b*S+tid]     : 0.0f;
  const float p1 = (tid+256 < S) ? (e1/den)*masks[b*S+tid+256] : 0.0f;
  red[tid] = p0 + p1;
  __syncthreads();
  for (int off=128; off>0; off>>=1){ if (tid<off) red[tid]+=red[tid+off]; __syncthreads(); }
  const float inv = 1.0f/(red[0] + 1e-12f);
  __syncthreads();
  const float pr0 = p0*inv, pr1 = p1*inv;
  sp[tid] = pr0; sp[tid+256] = pr1;
  if (hc==0){
    if (tid < S){ probs[b*S+tid] = pr0; cov[b*S+tid] += pr0; }
    if (tid+256 < S){ probs[b*S+tid+256] = pr1; cov[b*S+tid+256] += pr1; }
  }
  __syncthreads();
  const int c = tid & 63, sg_ = tid >> 6;
  const float* eb = enc + (size_t)b*S*H + hc*64 + c;
  float acc = 0.0f;
  for (int s=sg_; s<S; s+=4) acc += sp[s]*eb[(size_t)s*H];
  red[tid] = acc;
  __syncthreads();
  if (tid < 64)
    ctx[b*H + hc*64 + tid] = red[tid]+red[tid+64]+red[tid+128]+red[tid+192];
}

// grid 32 x 256. blocks 0..15: hh multi-b (8 j-blocks x 2 b-halves).
// blocks 16..31: per-b p_gen + x_{t+1}.
__global__ __launch_bounds__(256) void k_post(const float* __restrict__ h,
    const float* __restrict__ ctxg, const float* __restrict__ xcur,
    const float* __restrict__ emb, int tnext,
    const float* __restrict__ W_ad, const float* __restrict__ b_ad,
    const float* __restrict__ W_pgen, const float* __restrict__ b_pgen,
    const float* __restrict__ W_xctx, const float* __restrict__ b_xctx,
    float* __restrict__ hh, float* __restrict__ pgen, float* __restrict__ xnext){
  const int blk = blockIdx.x, tid = threadIdx.x;
  if (blk < 16){
    const int gb = blk >> 1, bh = blk & 1, b0 = bh*8;
    __shared__ float xc[8][1024];
    __shared__ float sg[4][64][9];
    for (int b=0;b<8;++b)
      for (int k=tid;k<1024;k+=256)
        xc[b][k] = (k<H) ? h[(b0+b)*H + k] : ctxg[(b0+b)*H + (k-H)];
    __syncthreads();
    const int w = tid >> 6, l = tid & 63;
    const int j = gb*64 + l;
    const float* wr = W_ad + (size_t)j*(2*H);
    float acc[8];
    #pragma unroll
    for (int b=0;b<8;++b) acc[b]=0.0f;
    for (int k=w*256;k<w*256+256;k+=4){
      const float4 wv = *reinterpret_cast<const float4*>(wr + k);
      #pragma unroll
      for (int b=0;b<8;++b){
        const float4 xv = *reinterpret_cast<const float4*>(&xc[b][k]);
        acc[b] += xv.x*wv.x + xv.y*wv.y + xv.z*wv.z + xv.w*wv.w;
      }
    }
    #pragma unroll
    for (int b=0;b<8;++b) sg[w][l][b] = acc[b];
    __syncthreads();
    for (int i=tid;i<512;i+=256){
      const int jl = i & 63, b = i >> 6;
      hh[(b0+b)*H + gb*64 + jl] = sg[0][jl][b]+sg[1][jl][b]+sg[2][jl][b]+sg[3][jl][b] + b_ad[gb*64 + jl];
    }
  } else {
    const int b = blk - 16;
    __shared__ float sc_[H], sh_[H], sx_[E], se_[E];
    __shared__ float red[256];
    for (int i=tid;i<H;i+=256){ sc_[i]=ctxg[b*H+i]; sh_[i]=h[b*H+i]; }
    if (tid < E){ sx_[tid]=xcur[b*E+tid]; se_[tid]=emb[(size_t)(b*T+tnext)*E+tid]; }
    __syncthreads();
    float part = 0.0f;
    for (int k=tid;k<2*H+E;k+=256){
      const float v = (k<H) ? sc_[k] : ((k<2*H) ? sh_[k-H] : sx_[k-2*H]);
      part += v * W_pgen[k];
    }
    red[tid] = part;
    __syncthreads();
    for (int off=128; off>0; off>>=1){ if (tid<off) red[tid]+=red[tid+off]; __syncthreads(); }
    if (tid==0) pgen[b] = fsig(red[0] + b_pgen[0]);
    if (tid < E){
      const float* wr = W_xctx + (size_t)tid*(E+H);
      float a = b_xctx[tid];
      #pragma unroll 8
      for (int k=0;k<E;k+=4){
        const float4 wv = *reinterpret_cast<const float4*>(wr+k);
        a += se_[k]*wv.x + se_[k+1]*wv.y + se_[k+2]*wv.z + se_[k+3]*wv.w;
      }
      #pragma unroll 8
      for (int k=0;k<H;k+=4){
        const float4 wv = *reinterpret_cast<const float4*>(wr+E+k);
        a += sc_[k]*wv.x + sc_[k+1]*wv.y + sc_[k+2]*wv.z + sc_[k+3]*wv.w;
      }
      xnext[b*E + tid] = a;
    }
  }
}

// logits[b][v] = hh[b] . W_vocab[v] + b_vocab[v]; also accumulates sum(exp) -> vsum[b].
__global__ __launch_bounds__(256) void k_logits(const float* __restrict__ hh,
    const float* __restrict__ W_vocab, const float* __restrict__ b_vocab,
    float* __restrict__ logits, float* __restrict__ vsum){
  const int tid = threadIdx.x;
  const int lane = tid & 63;
  const int w = __builtin_amdgcn_readfirstlane(tid >> 6);
  const int v = blockIdx.x*64 + lane;
  const float* wp = W_vocab + (size_t)v*H + w*128;
  const float* hp = hh + w*128;
  float acc[16];
  #pragma unroll
  for (int bb=0;bb<16;++bb) acc[bb]=0.0f;
  for (int k=0;k<128;k+=4){
    const float4 wv = *reinterpret_cast<const float4*>(wp + k);
    #pragma unroll
    for (int bb=0;bb<16;++bb){
      const float* hb = hp + bb*H;
      acc[bb] += hb[k]*wv.x + hb[k+1]*wv.y + hb[k+2]*wv.z + hb[k+3]*wv.w;
    }
  }
  __shared__ float red[4][64][17];
  __shared__ float es[16][65];
  #pragma unroll
  for (int bb=0;bb<16;++bb) red[w][lane][bb] = acc[bb];
  __syncthreads();
  for (int i=tid; i<1024; i+=256){
    const int bb = i >> 6, vl = i & 63;
    const int vv = blockIdx.x*64 + vl;
    const float zv = red[0][vl][bb]+red[1][vl][bb]+red[2][vl][bb]+red[3][vl][bb] + b_vocab[vv];
    logits[(size_t)bb*V + vv] = zv;
    es[bb][vl] = __expf(zv);
  }
  __syncthreads();
  {
    const int bb = tid >> 4, seg = tid & 15;
    float p = es[bb][seg*4] + es[bb][seg*4+1] + es[bb][seg*4+2] + es[bb][seg*4+3];
    p += __shfl_down(p, 8);
    p += __shfl_down(p, 4);
    p += __shfl_down(p, 2);
    p += __shfl_down(p, 1);
    if (seg == 0) atomicAdd(&vsum[bb], p);
  }
}

// grid (16 b, 33 chunks) x 256: pure streaming write of the output row.
__global__ __launch_bounds__(256) void k_final(const float* __restrict__ logits,
    const float* __restrict__ pg, const float* __restrict__ vsum,
    const float* __restrict__ exz, float* __restrict__ out, int t){
  const int b = blockIdx.x, c = blockIdx.y, tid = threadIdx.x;
  float* orow = out + (size_t)(b*T + t)*VEXT;
  if (c < 32){
    const float scl = pg[b]/vsum[b];
    const float* z = logits + (size_t)b*V + c*1000;
    for (int i=tid; i<1000; i+=256) orow[c*1000 + i] = __expf(z[i])*scl;
  } else if (tid < OOV){
    orow[V + tid] = exz[b*OOV + tid];
  }
}

// scatter for the last step (t = T-1), after its k_final.
__global__ __launch_bounds__(256) void k_scatter_last(const float* __restrict__ probs,
    const float* __restrict__ pg, const int* __restrict__ eidx,
    float* __restrict__ out){
  do_scatter(probs, pg, eidx, out, T-1, blockIdx.x*256 + threadIdx.x, 4*256);
}

} // namespace

extern "C" void kernel_launch(void* const* d_in, const int* in_sizes, int n_in,
                              void* d_out, int out_size, void* d_ws, size_t ws_size,
                              hipStream_t stream){
  const float* emb    = (const float*)d_in[0];
  const float* h0     = (const float*)d_in[1];
  const float* c0     = (const float*)d_in[2];
  const float* enc    = (const float*)d_in[3];
  const float* masks  = (const float*)d_in[4];
  const float* exz    = (const float*)d_in[5];
  const int*   eidx   = (const int*)d_in[6];
  const float* W_ih   = (const float*)d_in[7];
  const float* W_hh   = (const float*)d_in[8];
  const float* b_ih   = (const float*)d_in[9];
  const float* b_hh   = (const float*)d_in[10];
  const float* W_vocab= (const float*)d_in[11];
  const float* b_vocab= (const float*)d_in[12];
  const float* W_cov  = (const float*)d_in[13];
  const float* W_energy=(const float*)d_in[14];
  const float* b_energy=(const float*)d_in[15];
  const float* v_attn = (const float*)d_in[16];
  const float* W_xctx = (const float*)d_in[17];
  const float* b_xctx = (const float*)d_in[18];
  const float* W_ad   = (const float*)d_in[19];
  const float* b_ad   = (const float*)d_in[20];
  const float* W_pgen = (const float*)d_in[21];
  const float* b_pgen = (const float*)d_in[22];

  float* ws = (float*)d_ws;
  float* hbuf  = ws;             // 2 x 8192
  float* cbuf  = ws + 16384;     // 2 x 8192
  float* ctx   = ws + 32768;     // 8192
  float* xbuf  = ws + 40960;     // 2 x 2048
  float* dec   = ws + 45056;     // 8192
  float* hh    = ws + 53248;     // 8192
  float* pg    = ws + 61440;     // 16
  float* vsum  = ws + 61456;     // 16
  float* score = ws + 61472;     // 6400
  float* probs = ws + 67872;     // 6400
  float* cov   = ws + 74272;     // 6400
  float* logits= ws + 80672;     // 512000
  float* encp  = ws + 592672;    // 3276800
  float* Wt    = logits;         // 262144, aliased: used only before first k_logits
  float* outp  = (float*)d_out;

  k_init<<<32,256,0,stream>>>(h0,c0,hbuf,cbuf,cov);
  k_x0<<<16,128,0,stream>>>(emb,W_xctx,b_xctx,xbuf);
  k_trw<<<dim3(16,16),256,0,stream>>>(W_energy,Wt);
  k_encproj<<<400,512,0,stream>>>(enc,Wt,b_energy,encp);
  for (int t=0;t<T;++t){
    const int p = t&1;
    const float* hold = hbuf + p*8192;
    const float* cold = cbuf + p*8192;
    float* hnew = hbuf + (p^1)*8192;
    float* cnew = cbuf + (p^1)*8192;
    const float* xcur = xbuf + p*2048;
    float* xnext = xbuf + (p^1)*2048;
    const int tnext = (t+1 < T) ? (t+1) : (T-1);
    k_gates<<<68,256,0,stream>>>(xcur,hold,cold,W_ih,W_hh,b_ih,b_hh,hnew,cnew,
                                 probs,pg,eidx,outp,t);
    k_dec<<<16,256,0,stream>>>(hnew,W_energy,dec);
    k_score<<<dim3(100,16),256,0,stream>>>(dec,encp,W_cov,v_attn,cov,score);
    k_ctx<<<dim3(16,8),256,0,stream>>>(score,masks,enc,cov,probs,ctx,vsum);
    k_post<<<32,256,0,stream>>>(hnew,ctx,xcur,emb,tnext,W_ad,b_ad,W_pgen,b_pgen,
                                W_xctx,b_xctx,hh,pg,xnext);
    k_logits<<<500,256,0,stream>>>(hh,W_vocab,b_vocab,logits,vsum);
    k_final<<<dim3(16,33),256,0,stream>>>(logits,pg,vsum,exz,outp,t);
  }
  k_scatter_last<<<4,256,0,stream>>>(probs,pg,eidx,outp);
}